// Round 6
// baseline (238.522 us; speedup 1.0000x reference)
//
#include <hip/hip_runtime.h>
#include <stdint.h>

// MomentumLIF: x[N,T,D] f32 -> spikes[N,T,D] f32 (0/1)
//   v_t = mom*v + x_t - lamb*u ; u_t = 0.5*u + v_t ; s = (u>=1); u *= (1-s)
//
// R14: fused single kernel = R3's verified phase-split skeleton, upgraded.
//   Evidence so far: the t-strided read serves at a ~1.7 TB/s wall
//   (robust to occupancy 8->32 waves/CU, ring depth 2->16, barriers,
//   swizzle; HBM-side only 0.87 TB/s -- half of x is L3-resident). So the
//   read is a fixed ~77 us; the win left is hiding everything else under
//   it:
//   - no ws round-trip, no kernel B, no dispatch gap;
//   - PF=16 ring (128 KB/CU in flight, matches best-measured R0-A);
//   - spikes bitpacked to 8 SGPR-sized regs during the read loop, then
//     expanded and written as PLAIN (cached, not NT) float4 stores:
//     stores ack at the XCD L2, consume no load-tracking resources, and
//     writeback batching turns the strided 16B pieces into full-row
//     bursts. NT (R3) forced raw strided bursts at HBM = serial tail.
//   - XCD-chunk swizzle keeps one output row's dirty lines in ONE L2.
//   Counted-vmcnt discipline (R4 lesson): counted waits only ever see a
//   loads-only queue; all stores issue after the final vmcnt(0) drain.
//   Arithmetic order identical to the absmax==0 kernels (contract off).

#define N_ 64
#define T_ 64
#define D_ 8192
#define PF 16   // asm load ring depth (float4 tiles in flight per thread)
#define CPT 4   // chains per thread (one float4 of d)

typedef __attribute__((ext_vector_type(4))) float f32x4;

__global__ __launch_bounds__(256) void lif_fused(
    const float* __restrict__ x,
    const float* __restrict__ momp,
    const float* __restrict__ lambp,
    float* __restrict__ out)
{
    // Match numpy f32 semantics exactly: no FMA contraction anywhere.
#pragma clang fp contract(off)
    float mom  = momp[0];
    float lamb = lambp[0];
    const float decay = 0.5f;   // 1 - 1/TAU, exact

    // Pin scalars to SGPRs; vmcnt arithmetic must see only our asm loads.
    asm volatile("" : "+s"(mom), "+s"(lamb));

    // XCD-chunked swizzle: hw bid b lands on XCD b%8; remap so XCD j owns
    // 64 consecutive logical blocks = 8 contiguous n-slabs. 512 = 8*64
    // exactly -> bijective.
    const int bid  = (int)blockIdx.x;
    const int lbid = (bid & 7) * 64 + (bid >> 3);

    const int g  = lbid * 256 + (int)threadIdx.x;  // 0 .. N*D/4 - 1
    const int n  = g >> 11;                  // g / (D_/CPT)
    const int dq = g & 2047;                 // float4 index within a row
    const size_t base = (size_t)n * (size_t)(T_ * D_) + ((size_t)dq << 2);

    const f32x4* __restrict__ xv = reinterpret_cast<const f32x4*>(x + base);
    f32x4* __restrict__ ov       = reinterpret_cast<f32x4*>(out + base);
    const int RS = D_ / 4;                   // row stride in f32x4 units

    // Drain compiler-tracked vmem (momp/lambp loads) before our counting.
    asm volatile("s_waitcnt vmcnt(0)" ::: "memory");

    // ---------------- Phase 1: asm read ring + recurrence ----------------
    f32x4 xs[PF];
#pragma unroll
    for (int i = 0; i < PF; ++i) {
        const f32x4* a = xv + (size_t)i * RS;
        asm volatile("global_load_dwordx4 %0, %1, off" : "=v"(xs[i]) : "v"(a));
    }

    float u[CPT] = {0.f, 0.f, 0.f, 0.f};
    float v[CPT] = {0.f, 0.f, 0.f, 0.f};
    uint32_t blo[CPT] = {0u, 0u, 0u, 0u};    // spike bits t<32
    uint32_t bhi[CPT] = {0u, 0u, 0u, 0u};    // spike bits t>=32

#pragma unroll
    for (int t = 0; t < T_ - PF; ++t) {
        const int slot = t & (PF - 1);
        asm volatile("s_waitcnt vmcnt(15)" : "+v"(xs[slot]));
        const f32x4 xt = xs[slot];
        const f32x4* a = xv + (size_t)(t + PF) * RS;
        asm volatile("global_load_dwordx4 %0, %1, off" : "=v"(xs[slot]) : "v"(a));

#pragma unroll
        for (int c = 0; c < CPT; ++c) {
            const float t1 = mom * v[c];     // separately rounded, matches numpy
            const float t2 = lamb * u[c];
            v[c] = (t1 + xt[c]) - t2;
            u[c] = decay * u[c] + v[c];
            const bool sp = (u[c] >= 1.0f);
            if (t < 32) blo[c] |= ((uint32_t)sp) << t;
            else        bhi[c] |= ((uint32_t)sp) << (t - 32);
            u[c] = sp ? 0.0f : u[c];         // u*(1-s) is exactly this select
        }
    }

    // Drain ALL loads; after this point the vmem queue only ever holds
    // stores, and we never execute a counted wait again.
    asm volatile("s_waitcnt vmcnt(0)"
                 : "+v"(xs[0]),  "+v"(xs[1]),  "+v"(xs[2]),  "+v"(xs[3]),
                   "+v"(xs[4]),  "+v"(xs[5]),  "+v"(xs[6]),  "+v"(xs[7]),
                   "+v"(xs[8]),  "+v"(xs[9]),  "+v"(xs[10]), "+v"(xs[11]),
                   "+v"(xs[12]), "+v"(xs[13]), "+v"(xs[14]), "+v"(xs[15]));

#pragma unroll
    for (int t = T_ - PF; t < T_; ++t) {     // drain the ring, no more loads
        const f32x4 xt = xs[t & (PF - 1)];
#pragma unroll
        for (int c = 0; c < CPT; ++c) {
            const float t1 = mom * v[c];
            const float t2 = lamb * u[c];
            v[c] = (t1 + xt[c]) - t2;
            u[c] = decay * u[c] + v[c];
            const bool sp = (u[c] >= 1.0f);
            if (t < 32) blo[c] |= ((uint32_t)sp) << t;
            else        bhi[c] |= ((uint32_t)sp) << (t - 32);
            u[c] = sp ? 0.0f : u[c];
        }
    }

    // ---------------- Phase 2: plain cached store burst ------------------
    // Strided 16B float4 pieces, but they land in the XCD L2 (fast ack,
    // no load-path resources) and write back as batched rows.
#pragma unroll
    for (int t = 0; t < T_; ++t) {
        f32x4 o;
#pragma unroll
        for (int c = 0; c < CPT; ++c) {
            const uint32_t w = (t < 32) ? blo[c] : bhi[c];
            o[c] = ((w >> (t & 31)) & 1u) ? 1.0f : 0.0f;
        }
        ov[(size_t)t * RS] = o;              // plain store (L2-cached)
    }
}

extern "C" void kernel_launch(void* const* d_in, const int* in_sizes, int n_in,
                              void* d_out, int out_size, void* d_ws, size_t ws_size,
                              hipStream_t stream) {
    const float* x    = (const float*)d_in[0];
    const float* momp = (const float*)d_in[1];
    const float* lamb = (const float*)d_in[2];
    float* out = (float*)d_out;

    dim3 block(256);
    dim3 grid((N_ * D_ / CPT) / 256);   // 512 blocks, one thread per 4 chains
    hipLaunchKernelGGL(lif_fused, grid, block, 0, stream, x, momp, lamb, out);
}

// Round 7
// 225.856 us; speedup vs baseline: 1.0561x; 1.0561x over previous
//
#include <hip/hip_runtime.h>
#include <stdint.h>

// MomentumLIF: x[N,T,D] f32 -> spikes[N,T,D] f32 (0/1)
//   v_t = mom*v + x_t - lamb*u ; u_t = 0.5*u + v_t ; s = (u>=1); u *= (1-s)
//
// R15 = R3's fused skeleton (best kernel-sum: 84 us) + NONTEMPORAL LOADS.
//   Wall evidence: t-strided read pinned at 77-84 us (~1.7 TB/s delivered)
//   across load width / occupancy / ring depth / barriers / swizzle; only
//   half the stream comes from HBM (FETCH 65.7 GB-KB) -- the limiter is the
//   cache hierarchy's service of this stream, not HBM. R6 implicated the
//   same machinery for writes (cached strided stores = +33 us vs NT).
//   So: take L2/L3 out of the READ path too -- `nt` bit on global_load
//   (evict-first/no-allocate). If the wall is allocation/victim machinery,
//   the read approaches HBM copy BW; if dur stays ~84 with FETCH doubled,
//   the wall is structural and we are at the floor.
//   - PF=16 ring (128 KB/CU in flight), loads-only counted vmcnt (R4
//     lesson: never count over a heterogeneous queue).
//   - Phase 2: NT float4 stores after full vmcnt(0) drain (R3-proven).
//   Arithmetic order identical to the absmax==0 kernels (contract off).

#define N_ 64
#define T_ 64
#define D_ 8192
#define PF 16   // asm load ring depth (float4 tiles in flight per thread)
#define CPT 4   // chains per thread (one float4 of d)

typedef __attribute__((ext_vector_type(4))) float f32x4;

__global__ __launch_bounds__(256) void lif_fused(
    const float* __restrict__ x,
    const float* __restrict__ momp,
    const float* __restrict__ lambp,
    float* __restrict__ out)
{
    // Match numpy f32 semantics exactly: no FMA contraction anywhere.
#pragma clang fp contract(off)
    float mom  = momp[0];
    float lamb = lambp[0];
    const float decay = 0.5f;   // 1 - 1/TAU, exact

    // Pin scalars to SGPRs; vmcnt arithmetic must see only our asm loads.
    asm volatile("" : "+s"(mom), "+s"(lamb));

    // XCD-chunked swizzle (neutral but harmless; keeps each XCD on 8
    // contiguous n-slabs). 512 = 8*64 exactly -> bijective.
    const int bid  = (int)blockIdx.x;
    const int lbid = (bid & 7) * 64 + (bid >> 3);

    const int g  = lbid * 256 + (int)threadIdx.x;  // 0 .. N*D/4 - 1
    const int n  = g >> 11;                  // g / (D_/CPT)
    const int dq = g & 2047;                 // float4 index within a row
    const size_t base = (size_t)n * (size_t)(T_ * D_) + ((size_t)dq << 2);

    const f32x4* __restrict__ xv = reinterpret_cast<const f32x4*>(x + base);
    f32x4* __restrict__ ov       = reinterpret_cast<f32x4*>(out + base);
    const int RS = D_ / 4;                   // row stride in f32x4 units

    // Drain compiler-tracked vmem (momp/lambp loads) before our counting.
    asm volatile("s_waitcnt vmcnt(0)" ::: "memory");

    // ---------------- Phase 1: NT asm read ring + recurrence -------------
    f32x4 xs[PF];
#pragma unroll
    for (int i = 0; i < PF; ++i) {
        const f32x4* a = xv + (size_t)i * RS;
        asm volatile("global_load_dwordx4 %0, %1, off nt"
                     : "=v"(xs[i]) : "v"(a));
    }

    float u[CPT] = {0.f, 0.f, 0.f, 0.f};
    float v[CPT] = {0.f, 0.f, 0.f, 0.f};
    uint32_t blo[CPT] = {0u, 0u, 0u, 0u};    // spike bits t<32
    uint32_t bhi[CPT] = {0u, 0u, 0u, 0u};    // spike bits t>=32

#pragma unroll
    for (int t = 0; t < T_ - PF; ++t) {
        const int slot = t & (PF - 1);
        asm volatile("s_waitcnt vmcnt(15)" : "+v"(xs[slot]));
        const f32x4 xt = xs[slot];
        const f32x4* a = xv + (size_t)(t + PF) * RS;
        asm volatile("global_load_dwordx4 %0, %1, off nt"
                     : "=v"(xs[slot]) : "v"(a));

#pragma unroll
        for (int c = 0; c < CPT; ++c) {
            const float t1 = mom * v[c];     // separately rounded, matches numpy
            const float t2 = lamb * u[c];
            v[c] = (t1 + xt[c]) - t2;
            u[c] = decay * u[c] + v[c];
            const bool sp = (u[c] >= 1.0f);
            if (t < 32) blo[c] |= ((uint32_t)sp) << t;
            else        bhi[c] |= ((uint32_t)sp) << (t - 32);
            u[c] = sp ? 0.0f : u[c];         // u*(1-s) is exactly this select
        }
    }

    // Drain ALL loads; after this point the vmem queue only ever holds
    // stores, and we never execute a counted wait again (R4 lesson).
    asm volatile("s_waitcnt vmcnt(0)"
                 : "+v"(xs[0]),  "+v"(xs[1]),  "+v"(xs[2]),  "+v"(xs[3]),
                   "+v"(xs[4]),  "+v"(xs[5]),  "+v"(xs[6]),  "+v"(xs[7]),
                   "+v"(xs[8]),  "+v"(xs[9]),  "+v"(xs[10]), "+v"(xs[11]),
                   "+v"(xs[12]), "+v"(xs[13]), "+v"(xs[14]), "+v"(xs[15]));

#pragma unroll
    for (int t = T_ - PF; t < T_; ++t) {     // drain the ring, no more loads
        const f32x4 xt = xs[t & (PF - 1)];
#pragma unroll
        for (int c = 0; c < CPT; ++c) {
            const float t1 = mom * v[c];
            const float t2 = lamb * u[c];
            v[c] = (t1 + xt[c]) - t2;
            u[c] = decay * u[c] + v[c];
            const bool sp = (u[c] >= 1.0f);
            if (t < 32) blo[c] |= ((uint32_t)sp) << t;
            else        bhi[c] |= ((uint32_t)sp) << (t - 32);
            u[c] = sp ? 0.0f : u[c];
        }
    }

    // ---------------- Phase 2: NT store burst (R3-proven) ----------------
#pragma unroll
    for (int t = 0; t < T_; ++t) {
        f32x4 o;
#pragma unroll
        for (int c = 0; c < CPT; ++c) {
            const uint32_t w = (t < 32) ? blo[c] : bhi[c];
            o[c] = ((w >> (t & 31)) & 1u) ? 1.0f : 0.0f;
        }
        __builtin_nontemporal_store(o, ov + (size_t)t * RS);
    }
}

extern "C" void kernel_launch(void* const* d_in, const int* in_sizes, int n_in,
                              void* d_out, int out_size, void* d_ws, size_t ws_size,
                              hipStream_t stream) {
    const float* x    = (const float*)d_in[0];
    const float* momp = (const float*)d_in[1];
    const float* lamb = (const float*)d_in[2];
    float* out = (float*)d_out;

    dim3 block(256);
    dim3 grid((N_ * D_ / CPT) / 256);   // 512 blocks, one thread per 4 chains
    hipLaunchKernelGGL(lif_fused, grid, block, 0, stream, x, momp, lamb, out);
}